// Round 8
// baseline (918.051 us; speedup 1.0000x reference)
//
#include <hip/hip_runtime.h>
#include <cstddef>

#define NN 50000
#define NE 800000
#define NPAD 50176
#define SCAN_BLOCKS 196   // ceil(NN/256)
#define BN_EPS 1e-5f
#define EB 192            // edges per block in edge MLP
#define NPB 64            // nodes per block in agg256_ci (4 waves x 16 groups)
#define NBPC ((NN + NPB - 1) / NPB)   // blocks per chunk = 782

// ---------------- CSR build ----------------
__global__ __launch_bounds__(256) void k_count_int(const int* __restrict__ dst,
                                                   int* __restrict__ cnt) {
    int e = blockIdx.x * 256 + threadIdx.x;
    if (e < NE) atomicAdd(&cnt[dst[e]], 1);
}

__global__ __launch_bounds__(256) void k_bsum(const int* __restrict__ cnt,
                                              int* __restrict__ bsum) {
    __shared__ int red[4];
    int i = blockIdx.x * 256 + threadIdx.x;
    int v = (i < NN) ? cnt[i] : 0;
    #pragma unroll
    for (int off = 32; off > 0; off >>= 1) v += __shfl_down(v, off, 64);
    int lane = threadIdx.x & 63, w = threadIdx.x >> 6;
    if (lane == 0) red[w] = v;
    __syncthreads();
    if (threadIdx.x == 0) bsum[blockIdx.x] = red[0] + red[1] + red[2] + red[3];
}

__global__ __launch_bounds__(256) void k_scan_bsum(int* __restrict__ bsum) {
    __shared__ int tmp[256];
    int t = threadIdx.x;
    int v = (t < SCAN_BLOCKS) ? bsum[t] : 0;
    tmp[t] = v;
    __syncthreads();
    #pragma unroll
    for (int off = 1; off < 256; off <<= 1) {
        int u = (t >= off) ? tmp[t - off] : 0;
        __syncthreads();
        tmp[t] += u;
        __syncthreads();
    }
    if (t < SCAN_BLOCKS) bsum[t] = tmp[t] - v;  // exclusive
}

__global__ __launch_bounds__(256) void k_scan_fin(const int* __restrict__ cnt,
                                                  const int* __restrict__ bsum,
                                                  int* __restrict__ row_start,
                                                  int* __restrict__ cursor,
                                                  float* __restrict__ dsq,
                                                  float* __restrict__ dinv) {
    __shared__ int tmp[256];
    int t = threadIdx.x;
    int i = blockIdx.x * 256 + t;
    int c = (i < NN) ? cnt[i] : 0;
    tmp[t] = c;
    __syncthreads();
    #pragma unroll
    for (int off = 1; off < 256; off <<= 1) {
        int u = (t >= off) ? tmp[t - off] : 0;
        __syncthreads();
        tmp[t] += u;
        __syncthreads();
    }
    int excl = tmp[t] - c + bsum[blockIdx.x];
    if (i < NN) {
        row_start[i] = excl;
        cursor[i] = excl;
        float d = (float)c + 1.0f;
        dsq[i] = rsqrtf(d);
        dinv[i] = 1.0f / d;
    }
    if (i == 0) row_start[NN] = NE;
}

// fill packed CSR entries: low32 = src, high32 = dsq[src] bits
__global__ __launch_bounds__(256) void k_fill(const int* __restrict__ src,
                                              const int* __restrict__ dst,
                                              int* __restrict__ cursor,
                                              long long* __restrict__ pk,
                                              const float* __restrict__ dsq) {
    int e = blockIdx.x * 256 + threadIdx.x;
    if (e < NE) {
        int s = src[e];
        int pos = atomicAdd(&cursor[dst[e]], 1);
        unsigned long long v = (unsigned int)s |
            ((unsigned long long)(unsigned int)__float_as_int(dsq[s]) << 32);
        pk[pos] = (long long)v;
    }
}

// ---------------- fp32 tiled GEMM, 64x64 tile, optional fused BN+relu on A ----------------
template <bool BN>
__global__ __launch_bounds__(256) void k_gemm(const float* __restrict__ A,
                                              const float* __restrict__ B,
                                              float* __restrict__ C,
                                              int M, int K, int N,
                                              const float* __restrict__ stats,
                                              const float* __restrict__ g,
                                              const float* __restrict__ be) {
    __shared__ float As[16][68];
    __shared__ float Bs[16][68];
    const int tid = threadIdx.x;
    const int tx = tid & 15, ty = tid >> 4;
    const int row0 = blockIdx.y * 64, col0 = blockIdx.x * 64;
    float acc[4][4] = {};

    for (int kk = 0; kk < K; kk += 16) {
        #pragma unroll
        for (int i = 0; i < 4; ++i) {
            int idx = tid + i * 256;
            int m = idx >> 4, k = idx & 15;
            int gr = row0 + m;
            float v = (gr < M) ? A[(size_t)gr * K + kk + k] : 0.0f;
            if (BN) {
                int c = kk + k;
                v = fmaxf((v - stats[c]) * stats[K + c] * g[c] + be[c], 0.0f);
            }
            As[k][m] = v;
        }
        #pragma unroll
        for (int i = 0; i < 4; ++i) {
            int idx = tid + i * 256;
            int k = idx >> 6, n = idx & 63;
            Bs[k][n] = B[(size_t)(kk + k) * N + col0 + n];
        }
        __syncthreads();
        #pragma unroll
        for (int k = 0; k < 16; ++k) {
            float4 a4 = *reinterpret_cast<const float4*>(&As[k][ty * 4]);
            float4 b4 = *reinterpret_cast<const float4*>(&Bs[k][tx * 4]);
            float av[4] = {a4.x, a4.y, a4.z, a4.w};
            float bv[4] = {b4.x, b4.y, b4.z, b4.w};
            #pragma unroll
            for (int i = 0; i < 4; ++i)
                #pragma unroll
                for (int j = 0; j < 4; ++j)
                    acc[i][j] = fmaf(av[i], bv[j], acc[i][j]);
        }
        __syncthreads();
    }
    #pragma unroll
    for (int i = 0; i < 4; ++i) {
        int gr = row0 + ty * 4 + i;
        if (gr < M) {
            float4 v = make_float4(acc[i][0], acc[i][1], acc[i][2], acc[i][3]);
            *reinterpret_cast<float4*>(&C[(size_t)gr * N + col0 + tx * 4]) = v;
        }
    }
}

// ---------------- fp32 GEMM, 128x128 tile, 8x8 micro, BK=8, CHUNK-INTERLEAVED output ----
// C layout: [N/16][M][16]  (chunk-interleaved columns)
__global__ __launch_bounds__(256) void k_gemm128_ci(const float* __restrict__ A,
                                                    const float* __restrict__ B,
                                                    float* __restrict__ C,
                                                    int M, int K, int N) {
    __shared__ float As[8][132];
    __shared__ float Bs[8][132];
    const int tid = threadIdx.x;
    const int tx = tid & 15, ty = tid >> 4;
    const int row0 = blockIdx.y * 128, col0 = blockIdx.x * 128;
    float acc[8][8] = {};

    for (int kk = 0; kk < K; kk += 8) {
        {
            int m = tid >> 1;
            int k4 = (tid & 1) * 4;
            int gr = row0 + m;
            float4 v = make_float4(0.f, 0.f, 0.f, 0.f);
            if (gr < M) v = *reinterpret_cast<const float4*>(&A[(size_t)gr * K + kk + k4]);
            As[k4 + 0][m] = v.x;
            As[k4 + 1][m] = v.y;
            As[k4 + 2][m] = v.z;
            As[k4 + 3][m] = v.w;
        }
        {
            int k = tid >> 5;
            int n = (tid & 31) * 4;
            *reinterpret_cast<float4*>(&Bs[k][n]) =
                *reinterpret_cast<const float4*>(&B[(size_t)(kk + k) * N + col0 + n]);
        }
        __syncthreads();
        #pragma unroll
        for (int k = 0; k < 8; ++k) {
            float a[8], b[8];
            *reinterpret_cast<float4*>(&a[0]) = *reinterpret_cast<const float4*>(&As[k][ty * 4]);
            *reinterpret_cast<float4*>(&a[4]) = *reinterpret_cast<const float4*>(&As[k][64 + ty * 4]);
            *reinterpret_cast<float4*>(&b[0]) = *reinterpret_cast<const float4*>(&Bs[k][tx * 4]);
            *reinterpret_cast<float4*>(&b[4]) = *reinterpret_cast<const float4*>(&Bs[k][64 + tx * 4]);
            #pragma unroll
            for (int i = 0; i < 8; ++i)
                #pragma unroll
                for (int j = 0; j < 8; ++j)
                    acc[i][j] = fmaf(a[i], b[j], acc[i][j]);
        }
        __syncthreads();
    }
    const int c0a = col0 + tx * 4;
    const int c0b = col0 + 64 + tx * 4;
    float* pa = C + (size_t)(c0a >> 4) * ((size_t)M * 16) + (c0a & 15);
    float* pb = C + (size_t)(c0b >> 4) * ((size_t)M * 16) + (c0b & 15);
    #pragma unroll
    for (int i = 0; i < 8; ++i) {
        int gr = row0 + (i < 4 ? ty * 4 + i : 64 + ty * 4 + (i - 4));
        if (gr < M) {
            float4 v0 = make_float4(acc[i][0], acc[i][1], acc[i][2], acc[i][3]);
            float4 v1 = make_float4(acc[i][4], acc[i][5], acc[i][6], acc[i][7]);
            *reinterpret_cast<float4*>(pa + (size_t)gr * 16) = v0;
            *reinterpret_cast<float4*>(pb + (size_t)gr * 16) = v1;
        }
    }
}

// ---------------- chunked CSR aggregation, D=256, XCD-affine, float4 lanes ----------------
// hC: [16][NN][16] chunk-interleaved; out: [NN][256] row-major
// 4-lane group per node: lane q = lane&3 owns cols q*4..q*4+3 of the 16-col chunk.
__global__ __launch_bounds__(256) void k_agg256_ci(const float* __restrict__ hC,
                                                   const int* __restrict__ row_start,
                                                   const long long* __restrict__ pk,
                                                   const float* __restrict__ dsq,
                                                   const float* __restrict__ dinv,
                                                   const float* __restrict__ b,
                                                   float* __restrict__ out) {
    const int tid = threadIdx.x;
    const int lane = tid & 63;
    const int wave = tid >> 6;
    const int q = lane & 3;         // quad index within group
    const int grp = lane >> 2;      // group (node) within wave, 0..15
    const int gbase = lane & ~3;    // group's base lane for shfl

    const int bid = blockIdx.x;
    const int xcd = bid & 7;
    const int l = bid >> 3;               // 0 .. 2*NBPC-1
    const int half = (l >= NBPC) ? 1 : 0;
    const int chunk = xcd + (half << 3);
    const int blk = l - half * NBPC;

    const float* __restrict__ hk = hC + (size_t)chunk * ((size_t)NN * 16);
    const int d = blk * NPB + wave * 16 + grp;

    int rs = 0, re = 0;
    if (d < NN) {
        rs = row_start[d];
        re = row_start[d + 1];
    }
    float4 acc = make_float4(0.f, 0.f, 0.f, 0.f);
    for (int t = rs; t < re; t += 4) {
        int idx = t + q;
        long long pv = 0;
        if (idx < re) pv = __builtin_nontemporal_load(&pk[idx]);
        int px = (int)(unsigned int)((unsigned long long)pv & 0xffffffffull);
        int py = (int)(unsigned int)((unsigned long long)pv >> 32);
        #pragma unroll
        for (int i = 0; i < 4; ++i) {
            int s = __shfl(px, gbase + i, 64);
            float w = __int_as_float(__shfl(py, gbase + i, 64));
            float4 v = *reinterpret_cast<const float4*>(hk + (size_t)s * 16 + q * 4);
            acc.x = fmaf(v.x, w, acc.x);
            acc.y = fmaf(v.y, w, acc.y);
            acc.z = fmaf(v.z, w, acc.z);
            acc.w = fmaf(v.w, w, acc.w);
        }
    }
    if (d < NN) {
        float sd = dsq[d], di = dinv[d];
        float4 hv = *reinterpret_cast<const float4*>(hk + (size_t)d * 16 + q * 4);
        float4 bv = *reinterpret_cast<const float4*>(b + chunk * 16 + q * 4);
        float4 o;
        o.x = fmaf(acc.x, sd, fmaf(hv.x, di, bv.x));
        o.y = fmaf(acc.y, sd, fmaf(hv.y, di, bv.y));
        o.z = fmaf(acc.z, sd, fmaf(hv.z, di, bv.z));
        o.w = fmaf(acc.w, sd, fmaf(hv.w, di, bv.w));
        *reinterpret_cast<float4*>(out + (size_t)d * 256 + chunk * 16 + q * 4) = o;
    }
}

// ---------------- CSR aggregation, D=64 (packed entries) ----------------
template <bool RELU>
__global__ __launch_bounds__(256) void k_agg64(const float* __restrict__ h,
                                               const int* __restrict__ row_start,
                                               const long long* __restrict__ pk,
                                               const float* __restrict__ dsq,
                                               const float* __restrict__ dinv,
                                               const float* __restrict__ b,
                                               float* __restrict__ out) {
    int d = blockIdx.x * 4 + (threadIdx.x >> 6);
    if (d >= NN) return;
    int lane = threadIdx.x & 63;
    int rs = row_start[d], re = row_start[d + 1];
    float acc = 0.0f;
    for (int j = rs; j < re; ++j) {
        long long pv = pk[j];
        int s = (int)(unsigned int)((unsigned long long)pv & 0xffffffffull);
        float w = __int_as_float((int)(unsigned int)((unsigned long long)pv >> 32));
        acc = fmaf(h[(size_t)s * 64 + lane], w, acc);
    }
    float o = fmaf(acc, dsq[d], fmaf(h[(size_t)d * 64 + lane], dinv[d], b[lane]));
    if (RELU) o = fmaxf(o, 0.0f);
    out[(size_t)d * 64 + lane] = o;
}

// ---------------- BatchNorm stats ----------------
template <int C>
__global__ __launch_bounds__(256) void k_bn_stats(const float* __restrict__ x,
                                                  float* __restrict__ stats) {
    int c = threadIdx.x & (C - 1);
    int rstart = blockIdx.x * (256 / C) + (threadIdx.x / C);
    int rstride = gridDim.x * (256 / C);
    float s = 0.0f, ss = 0.0f;
    for (int r = rstart; r < NN; r += rstride) {
        float v = x[(size_t)r * C + c];
        s += v;
        ss += v * v;
    }
    atomicAdd(&stats[c], s);
    atomicAdd(&stats[C + c], ss);
}

__global__ __launch_bounds__(256) void k_bn_fin(float* __restrict__ stats, int C) {
    int c = threadIdx.x;
    if (c < C) {
        const float invN = 1.0f / (float)NN;
        float mean = stats[c] * invN;
        float var = stats[C + c] * invN - mean * mean;
        stats[c] = mean;
        stats[C + c] = rsqrtf(var + BN_EPS);
    }
}

// ---------------- edge MLP: block-batched, coalesced gather ----------------
__global__ __launch_bounds__(EB) void k_edge_mlp3(const float* __restrict__ A,
                                                  const float* __restrict__ B,
                                                  const int* __restrict__ src,
                                                  const int* __restrict__ dst,
                                                  const float* __restrict__ b1,
                                                  const float* __restrict__ W2,
                                                  const float* __restrict__ b2,
                                                  const float* __restrict__ W3,
                                                  const float* __restrict__ b3,
                                                  float* __restrict__ out) {
    __shared__ float h1s[EB][65];
    const int tid = threadIdx.x;
    const int w = tid >> 6, lane = tid & 63;
    const int base = blockIdx.x * EB + w * 64;

    int ee = base + lane;
    if (ee >= NE) ee = NE - 1;
    int se = src[ee];
    int de = dst[ee];
    float b1v = b1[lane];

    #pragma unroll 8
    for (int i = 0; i < 64; ++i) {
        int s = __shfl(se, i, 64);
        int d = __shfl(de, i, 64);
        float v = A[(size_t)s * 64 + lane] + B[(size_t)d * 64 + lane] + b1v;
        h1s[w * 64 + i][lane] = fmaxf(v, 0.0f);
    }
    __syncthreads();

    int e = blockIdx.x * EB + tid;
    if (e >= NE) return;

    float h2[32];
    #pragma unroll
    for (int j = 0; j < 32; ++j) h2[j] = b2[j];
    #pragma unroll
    for (int k = 0; k < 64; ++k) {
        float hk = h1s[tid][k];
        const float* wr = W2 + (size_t)k * 32;
        #pragma unroll
        for (int j = 0; j < 32; ++j) h2[j] = fmaf(hk, wr[j], h2[j]);
    }

    float o0 = b3[0], o1 = b3[1];
    #pragma unroll
    for (int k = 0; k < 32; ++k) {
        float hk = fmaxf(h2[k], 0.0f);
        o0 = fmaf(hk, W3[2 * k + 0], o0);
        o1 = fmaf(hk, W3[2 * k + 1], o1);
    }
    *reinterpret_cast<float2*>(out + (size_t)2 * e) = make_float2(o0, o1);
}

// ---------------- launch ----------------
extern "C" void kernel_launch(void* const* d_in, const int* in_sizes, int n_in,
                              void* d_out, int out_size, void* d_ws, size_t ws_size,
                              hipStream_t stream) {
    const float* x    = (const float*)d_in[0];
    const int*   ei   = (const int*)d_in[1];
    const int*   src  = ei;
    const int*   dst  = ei + NE;
    const float* W1   = (const float*)d_in[2];
    const float* b1   = (const float*)d_in[3];
    const float* g1   = (const float*)d_in[4];
    const float* be1  = (const float*)d_in[5];
    const float* W2   = (const float*)d_in[6];
    const float* b2   = (const float*)d_in[7];
    const float* g2   = (const float*)d_in[8];
    const float* be2  = (const float*)d_in[9];
    const float* W3   = (const float*)d_in[10];
    const float* b3   = (const float*)d_in[11];
    const float* We1  = (const float*)d_in[12];
    const float* bme1 = (const float*)d_in[13];
    const float* We2  = (const float*)d_in[14];
    const float* bme2 = (const float*)d_in[15];
    const float* We3  = (const float*)d_in[16];
    const float* bme3 = (const float*)d_in[17];
    float* out = (float*)d_out;
    char* ws = (char*)d_ws;

    float* dsq      = (float*)ws;                         ws += NPAD * 4;
    float* dinv     = (float*)ws;                         ws += NPAD * 4;
    float* stats    = (float*)ws;                         ws += 1024 * 4;
    int*   cnt      = (int*)ws;                           ws += NPAD * 4;
    int*   cursor   = (int*)ws;                           ws += NPAD * 4;
    int*   bsum     = (int*)ws;                           ws += 256 * 4;
    int*   row_start= (int*)ws;                           ws += (NPAD + 16) * 4;
    long long* pk   = (long long*)ws;                     ws += (size_t)NE * 8;
    float* bufH     = (float*)ws;                         ws += (size_t)NN * 256 * 4;
    float* bufO     = (float*)ws;

    const int nblkE = (NE + 255) / 256;
    const int nblkNode = (NN + 3) / 4;

    // ---- CSR build + degree terms ----
    hipMemsetAsync(cnt, 0, NPAD * sizeof(int), stream);
    k_count_int<<<nblkE, 256, 0, stream>>>(dst, cnt);
    k_bsum<<<SCAN_BLOCKS, 256, 0, stream>>>(cnt, bsum);
    k_scan_bsum<<<1, 256, 0, stream>>>(bsum);
    k_scan_fin<<<SCAN_BLOCKS, 256, 0, stream>>>(cnt, bsum, row_start, cursor, dsq, dinv);
    k_fill<<<nblkE, 256, 0, stream>>>(src, dst, cursor, pk, dsq);

    // ---- layer 1: 256 -> 256 (chunk-interleaved gemm), chunked agg, BN stats ----
    {
        dim3 g(2, (NN + 127) / 128);
        k_gemm128_ci<<<g, 256, 0, stream>>>(x, W1, bufH, NN, 256, 256);
    }
    k_agg256_ci<<<16 * NBPC, 256, 0, stream>>>(bufH, row_start, pk, dsq, dinv, b1, bufO);
    hipMemsetAsync(stats, 0, 1024 * sizeof(float), stream);
    k_bn_stats<256><<<256, 256, 0, stream>>>(bufO, stats);
    k_bn_fin<<<1, 256, 0, stream>>>(stats, 256);

    // ---- layer 2: A = BN1(bufO) fused; 256 -> 64; agg; BN2 stats ----
    {
        dim3 g(1, (NN + 63) / 64);
        k_gemm<true><<<g, 256, 0, stream>>>(bufO, W2, bufH, NN, 256, 64, stats, g1, be1);
    }
    k_agg64<false><<<nblkNode, 256, 0, stream>>>(bufH, row_start, pk, dsq, dinv, b2, bufO);
    hipMemsetAsync(stats, 0, 1024 * sizeof(float), stream);
    k_bn_stats<64><<<256, 256, 0, stream>>>(bufO, stats);
    k_bn_fin<<<1, 256, 0, stream>>>(stats, 64);

    // ---- layer 3: A = BN2(bufO) fused; 64 -> 64; agg + relu ----
    {
        dim3 g(1, (NN + 63) / 64);
        k_gemm<true><<<g, 256, 0, stream>>>(bufO, W3, bufH, NN, 64, 64, stats, g2, be2);
    }
    k_agg64<true><<<nblkNode, 256, 0, stream>>>(bufH, row_start, pk, dsq, dinv, b3, bufO);

    // ---- layer 4: 64 -> 64 (same W3/b3, no relu) -> emb in bufO ----
    {
        dim3 g(1, (NN + 63) / 64);
        k_gemm<false><<<g, 256, 0, stream>>>(bufO, W3, bufH, NN, 64, 64, nullptr, nullptr, nullptr);
    }
    k_agg64<false><<<nblkNode, 256, 0, stream>>>(bufH, row_start, pk, dsq, dinv, b3, bufO);

    // ---- edge MLP, factored layer 1 ----
    float* Abuf = bufH;
    float* Bbuf = bufH + (size_t)NN * 64;
    {
        dim3 g(1, (NN + 63) / 64);
        k_gemm<false><<<g, 256, 0, stream>>>(bufO, We1, Abuf, NN, 64, 64, nullptr, nullptr, nullptr);
        k_gemm<false><<<g, 256, 0, stream>>>(bufO, We1 + (size_t)64 * 64, Bbuf, NN, 64, 64, nullptr, nullptr, nullptr);
    }
    k_edge_mlp3<<<(NE + EB - 1) / EB, EB, 0, stream>>>(Abuf, Bbuf, src, dst, bme1, We2, bme2, We3, bme3, out);

    (void)in_sizes; (void)n_in; (void)out_size; (void)ws_size;
}

// Round 9
// 797.020 us; speedup vs baseline: 1.1519x; 1.1519x over previous
//
#include <hip/hip_runtime.h>
#include <cstddef>

#define NN 50000
#define NE 800000
#define NPAD 50176
#define SCAN_BLOCKS 196   // ceil(NN/256)
#define BN_EPS 1e-5f
#define EB 192            // edges per block in edge MLP

// ---------------- CSR build ----------------
__global__ __launch_bounds__(256) void k_count_int(const int* __restrict__ dst,
                                                   int* __restrict__ cnt) {
    int e = blockIdx.x * 256 + threadIdx.x;
    if (e < NE) atomicAdd(&cnt[dst[e]], 1);
}

__global__ __launch_bounds__(256) void k_bsum(const int* __restrict__ cnt,
                                              int* __restrict__ bsum) {
    __shared__ int red[4];
    int i = blockIdx.x * 256 + threadIdx.x;
    int v = (i < NN) ? cnt[i] : 0;
    #pragma unroll
    for (int off = 32; off > 0; off >>= 1) v += __shfl_down(v, off, 64);
    int lane = threadIdx.x & 63, w = threadIdx.x >> 6;
    if (lane == 0) red[w] = v;
    __syncthreads();
    if (threadIdx.x == 0) bsum[blockIdx.x] = red[0] + red[1] + red[2] + red[3];
}

__global__ __launch_bounds__(256) void k_scan_bsum(int* __restrict__ bsum) {
    __shared__ int tmp[256];
    int t = threadIdx.x;
    int v = (t < SCAN_BLOCKS) ? bsum[t] : 0;
    tmp[t] = v;
    __syncthreads();
    #pragma unroll
    for (int off = 1; off < 256; off <<= 1) {
        int u = (t >= off) ? tmp[t - off] : 0;
        __syncthreads();
        tmp[t] += u;
        __syncthreads();
    }
    if (t < SCAN_BLOCKS) bsum[t] = tmp[t] - v;  // exclusive
}

__global__ __launch_bounds__(256) void k_scan_fin(const int* __restrict__ cnt,
                                                  const int* __restrict__ bsum,
                                                  int* __restrict__ row_start,
                                                  int* __restrict__ cursor,
                                                  float* __restrict__ dsq,
                                                  float* __restrict__ dinv) {
    __shared__ int tmp[256];
    int t = threadIdx.x;
    int i = blockIdx.x * 256 + t;
    int c = (i < NN) ? cnt[i] : 0;
    tmp[t] = c;
    __syncthreads();
    #pragma unroll
    for (int off = 1; off < 256; off <<= 1) {
        int u = (t >= off) ? tmp[t - off] : 0;
        __syncthreads();
        tmp[t] += u;
        __syncthreads();
    }
    int excl = tmp[t] - c + bsum[blockIdx.x];
    if (i < NN) {
        row_start[i] = excl;
        cursor[i] = excl;
        float d = (float)c + 1.0f;
        dsq[i] = rsqrtf(d);
        dinv[i] = 1.0f / d;
    }
    if (i == 0) row_start[NN] = NE;
}

// fill packed CSR entries: low32 = src, high32 = dsq[src] bits
__global__ __launch_bounds__(256) void k_fill(const int* __restrict__ src,
                                              const int* __restrict__ dst,
                                              int* __restrict__ cursor,
                                              long long* __restrict__ pk,
                                              const float* __restrict__ dsq) {
    int e = blockIdx.x * 256 + threadIdx.x;
    if (e < NE) {
        int s = src[e];
        int pos = atomicAdd(&cursor[dst[e]], 1);
        unsigned long long v = (unsigned int)s |
            ((unsigned long long)(unsigned int)__float_as_int(dsq[s]) << 32);
        pk[pos] = (long long)v;
    }
}

// ---------------- fp32 tiled GEMM, 64x64 tile, optional fused BN+relu on A ----------------
template <bool BN>
__global__ __launch_bounds__(256) void k_gemm(const float* __restrict__ A,
                                              const float* __restrict__ B,
                                              float* __restrict__ C,
                                              int M, int K, int N,
                                              const float* __restrict__ stats,
                                              const float* __restrict__ g,
                                              const float* __restrict__ be) {
    __shared__ float As[16][68];
    __shared__ float Bs[16][68];
    const int tid = threadIdx.x;
    const int tx = tid & 15, ty = tid >> 4;
    const int row0 = blockIdx.y * 64, col0 = blockIdx.x * 64;
    float acc[4][4] = {};

    for (int kk = 0; kk < K; kk += 16) {
        #pragma unroll
        for (int i = 0; i < 4; ++i) {
            int idx = tid + i * 256;
            int m = idx >> 4, k = idx & 15;
            int gr = row0 + m;
            float v = (gr < M) ? A[(size_t)gr * K + kk + k] : 0.0f;
            if (BN) {
                int c = kk + k;
                v = fmaxf((v - stats[c]) * stats[K + c] * g[c] + be[c], 0.0f);
            }
            As[k][m] = v;
        }
        #pragma unroll
        for (int i = 0; i < 4; ++i) {
            int idx = tid + i * 256;
            int k = idx >> 6, n = idx & 63;
            Bs[k][n] = B[(size_t)(kk + k) * N + col0 + n];
        }
        __syncthreads();
        #pragma unroll
        for (int k = 0; k < 16; ++k) {
            float4 a4 = *reinterpret_cast<const float4*>(&As[k][ty * 4]);
            float4 b4 = *reinterpret_cast<const float4*>(&Bs[k][tx * 4]);
            float av[4] = {a4.x, a4.y, a4.z, a4.w};
            float bv[4] = {b4.x, b4.y, b4.z, b4.w};
            #pragma unroll
            for (int i = 0; i < 4; ++i)
                #pragma unroll
                for (int j = 0; j < 4; ++j)
                    acc[i][j] = fmaf(av[i], bv[j], acc[i][j]);
        }
        __syncthreads();
    }
    #pragma unroll
    for (int i = 0; i < 4; ++i) {
        int gr = row0 + ty * 4 + i;
        if (gr < M) {
            float4 v = make_float4(acc[i][0], acc[i][1], acc[i][2], acc[i][3]);
            *reinterpret_cast<float4*>(&C[(size_t)gr * N + col0 + tx * 4]) = v;
        }
    }
}

// ---------------- fp32 GEMM, 128x128 tile, 8x8 micro (split 4+4), BK=8 ----------------
__global__ __launch_bounds__(256) void k_gemm128(const float* __restrict__ A,
                                                 const float* __restrict__ B,
                                                 float* __restrict__ C,
                                                 int M, int K, int N) {
    __shared__ float As[8][132];
    __shared__ float Bs[8][132];
    const int tid = threadIdx.x;
    const int tx = tid & 15, ty = tid >> 4;
    const int row0 = blockIdx.y * 128, col0 = blockIdx.x * 128;
    float acc[8][8] = {};

    for (int kk = 0; kk < K; kk += 8) {
        {
            int m = tid >> 1;
            int k4 = (tid & 1) * 4;
            int gr = row0 + m;
            float4 v = make_float4(0.f, 0.f, 0.f, 0.f);
            if (gr < M) v = *reinterpret_cast<const float4*>(&A[(size_t)gr * K + kk + k4]);
            As[k4 + 0][m] = v.x;
            As[k4 + 1][m] = v.y;
            As[k4 + 2][m] = v.z;
            As[k4 + 3][m] = v.w;
        }
        {
            int k = tid >> 5;
            int n = (tid & 31) * 4;
            *reinterpret_cast<float4*>(&Bs[k][n]) =
                *reinterpret_cast<const float4*>(&B[(size_t)(kk + k) * N + col0 + n]);
        }
        __syncthreads();
        #pragma unroll
        for (int k = 0; k < 8; ++k) {
            float a[8], b[8];
            *reinterpret_cast<float4*>(&a[0]) = *reinterpret_cast<const float4*>(&As[k][ty * 4]);
            *reinterpret_cast<float4*>(&a[4]) = *reinterpret_cast<const float4*>(&As[k][64 + ty * 4]);
            *reinterpret_cast<float4*>(&b[0]) = *reinterpret_cast<const float4*>(&Bs[k][tx * 4]);
            *reinterpret_cast<float4*>(&b[4]) = *reinterpret_cast<const float4*>(&Bs[k][64 + tx * 4]);
            #pragma unroll
            for (int i = 0; i < 8; ++i)
                #pragma unroll
                for (int j = 0; j < 8; ++j)
                    acc[i][j] = fmaf(a[i], b[j], acc[i][j]);
        }
        __syncthreads();
    }
    #pragma unroll
    for (int i = 0; i < 8; ++i) {
        int gr = row0 + (i < 4 ? ty * 4 + i : 64 + ty * 4 + (i - 4));
        if (gr < M) {
            float4 v0 = make_float4(acc[i][0], acc[i][1], acc[i][2], acc[i][3]);
            float4 v1 = make_float4(acc[i][4], acc[i][5], acc[i][6], acc[i][7]);
            *reinterpret_cast<float4*>(&C[(size_t)gr * N + col0 + tx * 4]) = v0;
            *reinterpret_cast<float4*>(&C[(size_t)gr * N + col0 + 64 + tx * 4]) = v1;
        }
    }
}

// ---------------- CSR aggregation, D=256: one wave per node, unroll-2 ----------------
__global__ __launch_bounds__(256) void k_agg256(const float* __restrict__ h,
                                                const int* __restrict__ row_start,
                                                const long long* __restrict__ pk,
                                                const float* __restrict__ dsq,
                                                const float* __restrict__ dinv,
                                                const float* __restrict__ b,
                                                float* __restrict__ out) {
    int d = blockIdx.x * 4 + (threadIdx.x >> 6);
    if (d >= NN) return;
    int lane = threadIdx.x & 63;
    int rs = row_start[d], re = row_start[d + 1];
    float4 acc0 = make_float4(0.f, 0.f, 0.f, 0.f);
    float4 acc1 = make_float4(0.f, 0.f, 0.f, 0.f);
    int j = rs;
    for (; j + 2 <= re; j += 2) {
        long long pv0 = __builtin_nontemporal_load(&pk[j]);
        long long pv1 = __builtin_nontemporal_load(&pk[j + 1]);
        int s0 = (int)(unsigned int)((unsigned long long)pv0 & 0xffffffffull);
        float w0 = __int_as_float((int)(unsigned int)((unsigned long long)pv0 >> 32));
        int s1 = (int)(unsigned int)((unsigned long long)pv1 & 0xffffffffull);
        float w1 = __int_as_float((int)(unsigned int)((unsigned long long)pv1 >> 32));
        float4 v0 = *reinterpret_cast<const float4*>(h + (size_t)s0 * 256 + lane * 4);
        float4 v1 = *reinterpret_cast<const float4*>(h + (size_t)s1 * 256 + lane * 4);
        acc0.x = fmaf(v0.x, w0, acc0.x);
        acc0.y = fmaf(v0.y, w0, acc0.y);
        acc0.z = fmaf(v0.z, w0, acc0.z);
        acc0.w = fmaf(v0.w, w0, acc0.w);
        acc1.x = fmaf(v1.x, w1, acc1.x);
        acc1.y = fmaf(v1.y, w1, acc1.y);
        acc1.z = fmaf(v1.z, w1, acc1.z);
        acc1.w = fmaf(v1.w, w1, acc1.w);
    }
    if (j < re) {
        long long pv0 = __builtin_nontemporal_load(&pk[j]);
        int s0 = (int)(unsigned int)((unsigned long long)pv0 & 0xffffffffull);
        float w0 = __int_as_float((int)(unsigned int)((unsigned long long)pv0 >> 32));
        float4 v0 = *reinterpret_cast<const float4*>(h + (size_t)s0 * 256 + lane * 4);
        acc0.x = fmaf(v0.x, w0, acc0.x);
        acc0.y = fmaf(v0.y, w0, acc0.y);
        acc0.z = fmaf(v0.z, w0, acc0.z);
        acc0.w = fmaf(v0.w, w0, acc0.w);
    }
    float sd = dsq[d], di = dinv[d];
    float4 hv = *reinterpret_cast<const float4*>(h + (size_t)d * 256 + lane * 4);
    float4 bv = *reinterpret_cast<const float4*>(b + lane * 4);
    float4 o;
    o.x = fmaf(acc0.x + acc1.x, sd, fmaf(hv.x, di, bv.x));
    o.y = fmaf(acc0.y + acc1.y, sd, fmaf(hv.y, di, bv.y));
    o.z = fmaf(acc0.z + acc1.z, sd, fmaf(hv.z, di, bv.z));
    o.w = fmaf(acc0.w + acc1.w, sd, fmaf(hv.w, di, bv.w));
    *reinterpret_cast<float4*>(out + (size_t)d * 256 + lane * 4) = o;
}

// ---------------- CSR aggregation, D=64 (packed entries) ----------------
template <bool RELU>
__global__ __launch_bounds__(256) void k_agg64(const float* __restrict__ h,
                                               const int* __restrict__ row_start,
                                               const long long* __restrict__ pk,
                                               const float* __restrict__ dsq,
                                               const float* __restrict__ dinv,
                                               const float* __restrict__ b,
                                               float* __restrict__ out) {
    int d = blockIdx.x * 4 + (threadIdx.x >> 6);
    if (d >= NN) return;
    int lane = threadIdx.x & 63;
    int rs = row_start[d], re = row_start[d + 1];
    float acc0 = 0.0f, acc1 = 0.0f;
    int j = rs;
    for (; j + 2 <= re; j += 2) {
        long long pv0 = pk[j];
        long long pv1 = pk[j + 1];
        int s0 = (int)(unsigned int)((unsigned long long)pv0 & 0xffffffffull);
        float w0 = __int_as_float((int)(unsigned int)((unsigned long long)pv0 >> 32));
        int s1 = (int)(unsigned int)((unsigned long long)pv1 & 0xffffffffull);
        float w1 = __int_as_float((int)(unsigned int)((unsigned long long)pv1 >> 32));
        acc0 = fmaf(h[(size_t)s0 * 64 + lane], w0, acc0);
        acc1 = fmaf(h[(size_t)s1 * 64 + lane], w1, acc1);
    }
    if (j < re) {
        long long pv0 = pk[j];
        int s0 = (int)(unsigned int)((unsigned long long)pv0 & 0xffffffffull);
        float w0 = __int_as_float((int)(unsigned int)((unsigned long long)pv0 >> 32));
        acc0 = fmaf(h[(size_t)s0 * 64 + lane], w0, acc0);
    }
    float o = fmaf(acc0 + acc1, dsq[d], fmaf(h[(size_t)d * 64 + lane], dinv[d], b[lane]));
    if (RELU) o = fmaxf(o, 0.0f);
    out[(size_t)d * 64 + lane] = o;
}

// ---------------- BatchNorm stats ----------------
template <int C>
__global__ __launch_bounds__(256) void k_bn_stats(const float* __restrict__ x,
                                                  float* __restrict__ stats) {
    int c = threadIdx.x & (C - 1);
    int rstart = blockIdx.x * (256 / C) + (threadIdx.x / C);
    int rstride = gridDim.x * (256 / C);
    float s = 0.0f, ss = 0.0f;
    for (int r = rstart; r < NN; r += rstride) {
        float v = x[(size_t)r * C + c];
        s += v;
        ss += v * v;
    }
    atomicAdd(&stats[c], s);
    atomicAdd(&stats[C + c], ss);
}

__global__ __launch_bounds__(256) void k_bn_fin(float* __restrict__ stats, int C) {
    int c = threadIdx.x;
    if (c < C) {
        const float invN = 1.0f / (float)NN;
        float mean = stats[c] * invN;
        float var = stats[C + c] * invN - mean * mean;
        stats[c] = mean;
        stats[C + c] = rsqrtf(var + BN_EPS);
    }
}

// ---------------- edge MLP: block-batched, coalesced gather ----------------
__global__ __launch_bounds__(EB) void k_edge_mlp3(const float* __restrict__ A,
                                                  const float* __restrict__ B,
                                                  const int* __restrict__ src,
                                                  const int* __restrict__ dst,
                                                  const float* __restrict__ b1,
                                                  const float* __restrict__ W2,
                                                  const float* __restrict__ b2,
                                                  const float* __restrict__ W3,
                                                  const float* __restrict__ b3,
                                                  float* __restrict__ out) {
    __shared__ float h1s[EB][65];
    const int tid = threadIdx.x;
    const int w = tid >> 6, lane = tid & 63;
    const int base = blockIdx.x * EB + w * 64;

    int ee = base + lane;
    if (ee >= NE) ee = NE - 1;
    int se = src[ee];
    int de = dst[ee];
    float b1v = b1[lane];

    #pragma unroll 8
    for (int i = 0; i < 64; ++i) {
        int s = __shfl(se, i, 64);
        int d = __shfl(de, i, 64);
        float v = A[(size_t)s * 64 + lane] + B[(size_t)d * 64 + lane] + b1v;
        h1s[w * 64 + i][lane] = fmaxf(v, 0.0f);
    }
    __syncthreads();

    int e = blockIdx.x * EB + tid;
    if (e >= NE) return;

    float h2[32];
    #pragma unroll
    for (int j = 0; j < 32; ++j) h2[j] = b2[j];
    #pragma unroll
    for (int k = 0; k < 64; ++k) {
        float hk = h1s[tid][k];
        const float* wr = W2 + (size_t)k * 32;
        #pragma unroll
        for (int j = 0; j < 32; ++j) h2[j] = fmaf(hk, wr[j], h2[j]);
    }

    float o0 = b3[0], o1 = b3[1];
    #pragma unroll
    for (int k = 0; k < 32; ++k) {
        float hk = fmaxf(h2[k], 0.0f);
        o0 = fmaf(hk, W3[2 * k + 0], o0);
        o1 = fmaf(hk, W3[2 * k + 1], o1);
    }
    *reinterpret_cast<float2*>(out + (size_t)2 * e) = make_float2(o0, o1);
}

// ---------------- launch ----------------
extern "C" void kernel_launch(void* const* d_in, const int* in_sizes, int n_in,
                              void* d_out, int out_size, void* d_ws, size_t ws_size,
                              hipStream_t stream) {
    const float* x    = (const float*)d_in[0];
    const int*   ei   = (const int*)d_in[1];
    const int*   src  = ei;
    const int*   dst  = ei + NE;
    const float* W1   = (const float*)d_in[2];
    const float* b1   = (const float*)d_in[3];
    const float* g1   = (const float*)d_in[4];
    const float* be1  = (const float*)d_in[5];
    const float* W2   = (const float*)d_in[6];
    const float* b2   = (const float*)d_in[7];
    const float* g2   = (const float*)d_in[8];
    const float* be2  = (const float*)d_in[9];
    const float* W3   = (const float*)d_in[10];
    const float* b3   = (const float*)d_in[11];
    const float* We1  = (const float*)d_in[12];
    const float* bme1 = (const float*)d_in[13];
    const float* We2  = (const float*)d_in[14];
    const float* bme2 = (const float*)d_in[15];
    const float* We3  = (const float*)d_in[16];
    const float* bme3 = (const float*)d_in[17];
    float* out = (float*)d_out;
    char* ws = (char*)d_ws;

    float* dsq      = (float*)ws;                         ws += NPAD * 4;
    float* dinv     = (float*)ws;                         ws += NPAD * 4;
    float* stats    = (float*)ws;                         ws += 1024 * 4;
    int*   cnt      = (int*)ws;                           ws += NPAD * 4;
    int*   cursor   = (int*)ws;                           ws += NPAD * 4;
    int*   bsum     = (int*)ws;                           ws += 256 * 4;
    int*   row_start= (int*)ws;                           ws += (NPAD + 16) * 4;
    long long* pk   = (long long*)ws;                     ws += (size_t)NE * 8;
    float* bufH     = (float*)ws;                         ws += (size_t)NN * 256 * 4;
    float* bufO     = (float*)ws;

    const int nblkE = (NE + 255) / 256;
    const int nblkNode = (NN + 3) / 4;

    // ---- CSR build + degree terms ----
    hipMemsetAsync(cnt, 0, NPAD * sizeof(int), stream);
    k_count_int<<<nblkE, 256, 0, stream>>>(dst, cnt);
    k_bsum<<<SCAN_BLOCKS, 256, 0, stream>>>(cnt, bsum);
    k_scan_bsum<<<1, 256, 0, stream>>>(bsum);
    k_scan_fin<<<SCAN_BLOCKS, 256, 0, stream>>>(cnt, bsum, row_start, cursor, dsq, dinv);
    k_fill<<<nblkE, 256, 0, stream>>>(src, dst, cursor, pk, dsq);

    // ---- layer 1: 256 -> 256, agg, BN stats (apply fused into next gemm) ----
    {
        dim3 g(2, (NN + 127) / 128);
        k_gemm128<<<g, 256, 0, stream>>>(x, W1, bufH, NN, 256, 256);
    }
    k_agg256<<<nblkNode, 256, 0, stream>>>(bufH, row_start, pk, dsq, dinv, b1, bufO);
    hipMemsetAsync(stats, 0, 1024 * sizeof(float), stream);
    k_bn_stats<256><<<256, 256, 0, stream>>>(bufO, stats);
    k_bn_fin<<<1, 256, 0, stream>>>(stats, 256);

    // ---- layer 2: A = BN1(bufO) fused; 256 -> 64; agg; BN2 stats ----
    {
        dim3 g(1, (NN + 63) / 64);
        k_gemm<true><<<g, 256, 0, stream>>>(bufO, W2, bufH, NN, 256, 64, stats, g1, be1);
    }
    k_agg64<false><<<nblkNode, 256, 0, stream>>>(bufH, row_start, pk, dsq, dinv, b2, bufO);
    hipMemsetAsync(stats, 0, 1024 * sizeof(float), stream);
    k_bn_stats<64><<<256, 256, 0, stream>>>(bufO, stats);
    k_bn_fin<<<1, 256, 0, stream>>>(stats, 64);

    // ---- layer 3: A = BN2(bufO) fused; 64 -> 64; agg + relu ----
    {
        dim3 g(1, (NN + 63) / 64);
        k_gemm<true><<<g, 256, 0, stream>>>(bufO, W3, bufH, NN, 64, 64, stats, g2, be2);
    }
    k_agg64<true><<<nblkNode, 256, 0, stream>>>(bufH, row_start, pk, dsq, dinv, b3, bufO);

    // ---- layer 4: 64 -> 64 (same W3/b3, no relu) -> emb in bufO ----
    {
        dim3 g(1, (NN + 63) / 64);
        k_gemm<false><<<g, 256, 0, stream>>>(bufO, W3, bufH, NN, 64, 64, nullptr, nullptr, nullptr);
    }
    k_agg64<false><<<nblkNode, 256, 0, stream>>>(bufH, row_start, pk, dsq, dinv, b3, bufO);

    // ---- edge MLP, factored layer 1 ----
    float* Abuf = bufH;
    float* Bbuf = bufH + (size_t)NN * 64;
    {
        dim3 g(1, (NN + 63) / 64);
        k_gemm<false><<<g, 256, 0, stream>>>(bufO, We1, Abuf, NN, 64, 64, nullptr, nullptr, nullptr);
        k_gemm<false><<<g, 256, 0, stream>>>(bufO, We1 + (size_t)64 * 64, Bbuf, NN, 64, 64, nullptr, nullptr, nullptr);
    }
    k_edge_mlp3<<<(NE + EB - 1) / EB, EB, 0, stream>>>(Abuf, Bbuf, src, dst, bme1, We2, bme2, We3, bme3, out);

    (void)in_sizes; (void)n_in; (void)out_size; (void)ws_size;
}